// Round 7
// baseline (358.051 us; speedup 1.0000x reference)
//
#include <hip/hip_runtime.h>

// InputPreprocessor — B=2048, N=32, M=8, D_PAIR=37, H=128.
// features_el_el in the reference is DEAD CODE. Live outputs (both f32):
//   out0 = features_el  [B,N,424]  (ion-summed 2-layer silu MLP || flat feats)
//   out1 = features_ion [B,8,32]
// R13: occupancy via L2-resident W1. R12 (VALUBusy 53%, 16 waves/CU) is
// latency-bound; LDS (49K of weights) caps blocks/CU, while VGPR=56 has slack.
//  - W1 B-frags moved out of LDS: prep_w1 kernel writes the bf16 frag layout
//    to d_ws (32 KB); el loads bw via wave-uniform coalesced dwordx4 (L2 hit,
//    ~17 TB/s aggregate << 35 TB/s ceiling; FETCH_SIZE counts HBM only).
//  - LDS = 16384 (W0L) + 30720 (UNI) = 47104 -> 3 blocks/CU = 24 waves/CU
//    (6/SIMD, 1.5x R12). __launch_bounds__(512,6): cap ~80 VGPR vs ~72 demand.
//  - bw staged in 4-wide groups (16 VGPRs in flight); per-iter opaque
//    asm("+s") barrier on w1 pointer blocks LICM from hoisting 32 frags
//    (128 regs) across iterations — the R11 spill trap.
//  - grid 768 = exactly 3/CU; blocks<256 run 6 iters, rest 5 (4096 block-
//    iters total, per-CU work balanced to ~6%).
// Carried from R12: cross-iter feat pipeline (featA/featB disjoint double
// buffer, branchless body, idempotent wrap), rolling h0c l0->l1 handoff
// (stride-40, bank-uniform), v_cvt_pk_bf16_f32, bias0 via 1.0-feature,
// b1/mu/sigma hoisted, 2-deep r prefetch, ion folded in, setprio around l1.

typedef __attribute__((ext_vector_type(8))) short short8;
typedef __attribute__((ext_vector_type(4))) float f32x4;

#define ROWLEN    424
#define OUT_EL    27787264    // 65536*424

__device__ __forceinline__ unsigned short f2bf(float f){   // prologue staging only
    unsigned int u = __builtin_bit_cast(unsigned int, f);
    u += 0x7fffu + ((u >> 16) & 1u);     // RNE
    return (unsigned short)(u >> 16);
}
__device__ __forceinline__ unsigned int cvtpk_bf16(float lo, float hi){
    unsigned int r;
    asm("v_cvt_pk_bf16_f32 %0, %1, %2" : "=v"(r) : "v"(lo), "v"(hi));
    return r;   // [15:0]=bf16(lo), [31:16]=bf16(hi), RNE
}
__device__ __forceinline__ unsigned short bf16s(float x){
    return (unsigned short)cvtpk_bf16(x, x);
}
__device__ __forceinline__ float fast_silu(float x){
    return x * __builtin_amdgcn_rcpf(1.0f + __expf(-x));
}

// W1 bf16 B-frag layout into d_ws: short i = [tc][c][lane][j],
// k = c*32 + (lane>>4)*8 + j, n = tc*16 + (lane&15).
__global__ __launch_bounds__(256)
void prep_w1(const float* __restrict__ W1, unsigned short* __restrict__ w1f)
{
    int i = blockIdx.x*256 + threadIdx.x;        // 16384 shorts total
    int j = i & 7, ln = (i >> 3) & 63, c = (i >> 9) & 3, tc = i >> 11;
    int k = c*32 + (ln >> 4)*8 + j, n = tc*16 + (ln & 15);
    w1f[i] = f2bf(W1[k*128 + n]);
}

__global__ __launch_bounds__(512, 6)
void el_kernel(const float* __restrict__ r,
               const float* __restrict__ Rion,
               const float* __restrict__ W0,
               const float* __restrict__ b0,
               const float* __restrict__ b1,
               const unsigned short* __restrict__ w1f,
               const float* __restrict__ Z,
               const float* __restrict__ Wion,
               const float* __restrict__ bion,
               float* __restrict__ out)
{
    // MFMA-read layouts are [tile][chunk][lane64][8 shorts]: b128 = base+lane*16.
    __shared__ __align__(16) unsigned short W0L[8][2][64][8];   // 16384 B
    // Per-wave 3840B, three DISJOINT regions (no aliasing, no barriers):
    //   shorts [0,640)     : featA (k<32: [4][16][8]; tails+1.0+pad: [16][8])
    //   shorts [640,1280)  : featB (same layout; double buffer)
    //   shorts [1280,1920) : h0c rolling [16 edges][40] (l0->l1 chunk handoff)
    __shared__ __align__(16) unsigned short UNI[8][1920];       // 30720 B
    // total 47104 B -> 3 blocks (1536 thr) / CU = 24 waves/CU (6/SIMD)

    const int t    = threadIdx.x;
    const int lane = t & 63;
    const int w    = t >> 6;       // wave 0..7, owns units 2w,2w+1 (16 edges)
    const int quad = lane >> 4;
    const int l16  = lane & 15;

    // ---- stage W0L: A-frag for layer 0 (M=channel, K=feature) ----
    for (int i = t; i < 8*2*64*8; i += 512){
        int j = i & 7, ln = (i >> 3) & 63, ch = (i >> 9) & 1, tc = i >> 10;
        int q = ln >> 4, n = tc*16 + (ln & 15);
        float v = 0.f;
        if (ch == 0)            v = W0[(q*8 + j)*128 + n];
        else if (q == 0){
            if      (j < 5)     v = W0[(32 + j)*128 + n];
            else if (j == 5)    v = b0[n];                 // bias via 1.0-feature
        }
        ((unsigned short*)W0L)[i] = f2bf(v);
    }
    // ---- constant tail slots, BOTH feat buffers, once:
    // slot 5 = 1.0 (bias feature), slots 6,7 = 0.0 (k=38,39 pad).
    // Without init, it=0 reads raw LDS garbage; bf16 Inf/NaN x 0.0 weight
    // row = NaN inside the layer-0 MFMA (R8 lesson).
    if (t < 128){
        int ww = t >> 4, e = t & 15;
        #pragma unroll
        for (int b = 0; b < 2; ++b){
            UNI[ww][b*640 + 512 + e*8 + 5] = 0x3F80;
            UNI[ww][b*640 + 512 + e*8 + 6] = 0;
            UNI[ww][b*640 + 512 + e*8 + 7] = 0;
        }
    }

    // ---- ion output folded in: blocks 0..511 write 2 elems/thread ----
    {
        int tid = blockIdx.x*512 + t;
        if (tid < 262144){
            int e0 = tid*2;                    // even -> j0 < 31, no wrap
            int j0 = e0 & 31, mm = (e0 >> 5) & 7;
            float z = Z[mm];
            float2 v;
            v.x = fast_silu(z * Wion[j0]     + bion[j0]);
            v.y = fast_silu(z * Wion[j0 + 1] + bion[j0 + 1]);
            *(float2*)&out[OUT_EL + e0] = v;
        }
    }

    // feature-phase mapping: 4 threads per edge; wave-local (frow>>4 == w)
    const int frow  = t >> 2;      // edge 0..127 = ul*8 + m
    const int phase = t & 3;
    const int ul    = frow >> 3;   // block-local unit 0..15
    const int m     = frow & 7;
    const int e16   = frow & 15;   // wave-local edge
    const float Rx = Rion[m*3+0];
    const float Ry = Rion[m*3+1];
    const float Rz = Rion[m*3+2];

    unsigned short* const uw = &UNI[w][0];

    const f32x4 zeroc = {0.f,0.f,0.f,0.f};

    // hoist layer-1 bias (8 VGPRs)
    float bias1[8];
    #pragma unroll
    for (int tc = 0; tc < 8; ++tc) bias1[tc] = b1[tc*16 + l16];

    // hoist per-thread RBF constants: f = phase + 4k, k = 0..7
    float muA[8], isA[8];
    #pragma unroll
    for (int kk = 0; kk < 8; ++kk){
        float q = (float)(phase + 4*kk) * (1.0f/31.0f);
        muA[kk] = q*q*5.0f;
        isA[kk] = 7.0f * __builtin_amdgcn_rcpf(1.0f + 5.0f*q);
    }

    // work split: blocks 0..255 -> 6 iters, 256..767 -> 5 iters
    // (256*96 + 512*80 = 65536 units; 16 units per block-iter)
    const int bid    = blockIdx.x;
    const int niter  = (bid < 256) ? 6 : 5;
    const int ubase0 = (bid < 256) ? bid*96 : 24576 + (bid - 256)*80;

    // Branchless feature pass: computes edge (gu, m)'s 37 features, stores
    // exact f32 to out and bf16 to feat buffer at short-offset fb.
    auto feat_pass = [&](int gu, int fb, float px, float py, float pz){
        float dx = px - Rx, dy = py - Ry, dz = pz - Rz;
        float d2 = dx*dx + dy*dy + dz*dz;
        float d  = __builtin_amdgcn_sqrtf(d2);
        float* orow = &out[(size_t)gu*ROWLEN + 128 + m*37];
        #pragma unroll
        for (int kk = 0; kk < 8; ++kk){
            float uu  = (d - muA[kk]) * isA[kk];
            float val = d2 * __expf(-d - uu*uu);
            orow[phase + 4*kk] = val;
            uw[fb + (kk >> 1)*128 + e16*8 + phase + ((kk & 1) << 2)] = bf16s(val);
        }
        // tails, branchless: this phase's slot + redundant dz (idempotent x4)
        float tv = (phase == 0) ? d :
                   (phase == 1) ? __builtin_amdgcn_rcpf(d + 0.01f) :
                   (phase == 2) ? dx : dy;
        orow[32 + phase] = tv;
        orow[36]         = dz;
        uw[fb + 512 + e16*8 + phase] = bf16s(tv);
        uw[fb + 512 + e16*8 + 4]     = bf16s(dz);
    };

    // ---- prologue: feat(0) into featA; prefetch r(1) ----
    {
        int gu = ubase0 + ul;
        feat_pass(gu, 0, r[gu*3+0], r[gu*3+1], r[gu*3+2]);
    }
    float cx, cy, cz;
    {
        int gu = ubase0 + 16 + ul;           // r(1) (niter >= 2)
        cx = r[gu*3+0]; cy = r[gu*3+1]; cz = r[gu*3+2];
    }

    __syncthreads();   // weights staged; loop body is wave-local, barrier-free

    int cur = 0;       // short-offset of current feat buffer (0 or 640)
    for (int it = 0; it < niter; ++it){
        const int ubase = ubase0 + it * 16;

        // opaque barrier: keeps w1f loads inside the loop (blocks LICM from
        // hoisting 32 frags = 128 VGPRs across iterations — R11 spill trap)
        const unsigned short* w1p = w1f;
        asm volatile("" : "+s"(w1p));

        // prefetch r((it+2) mod niter) — wrapped, branchless
        int i2 = it + 2; if (i2 >= niter) i2 -= niter;
        int gun = ubase0 + i2*16 + ul;
        float nx = r[gun*3+0], ny = r[gun*3+1], nz = r[gun*3+2];

        // current iteration's B-frags (featA/B[cur]; written a full iter ago)
        short8 bf0 = *(const short8*)&uw[cur + quad*128 + l16*8];   // k = quad*8+j
        short8 bf1 = *(const short8*)&uw[cur + 512 + l16*8];        // k = 32+j

        // feat for (it+1) mod niter into the OTHER buffer; last iter
        // recomputes feat(0) with identical values (idempotent stores).
        {
            int i1 = it + 1; if (i1 >= niter) i1 -= niter;
            int gu = ubase0 + i1*16 + ul;
            feat_pass(gu, cur ^ 640, cx, cy, cz);
        }

        // ---------- fused layer0/layer1, rolling h0 chunk ----------
        f32x4 acc1[8];
        #pragma unroll
        for (int i = 0; i < 8; ++i) acc1[i] = zeroc;

        #pragma unroll
        for (int c = 0; c < 4; ++c){
            // l0 steps tc=2c, 2c+1 produce exactly k-chunk c = [32c, 32c+32)
            #pragma unroll
            for (int h = 0; h < 2; ++h){
                const int tc = 2*c + h;
                short8 a0 = *(const short8*)&W0L[tc][0][lane][0];
                short8 a1 = *(const short8*)&W0L[tc][1][lane][0];
                f32x4 acc = __builtin_amdgcn_mfma_f32_16x16x32_bf16(a0, bf0, zeroc, 0, 0, 0);
                acc       = __builtin_amdgcn_mfma_f32_16x16x32_bf16(a1, bf1, acc,   0, 0, 0);
                // C-layout: lane holds ch n = tc*16 + quad*4 + rr, edge = l16.
                unsigned int p01 = cvtpk_bf16(fast_silu(acc[0]), fast_silu(acc[1]));
                unsigned int p23 = cvtpk_bf16(fast_silu(acc[2]), fast_silu(acc[3]));
                unsigned long long pk = (unsigned long long)p01 |
                                        ((unsigned long long)p23 << 32);
                // h0c[edge=l16][ch32 = h*16+quad*4 ..+3]; stride-40 rows:
                // b64 write = 4 accesses/bank uniform (conflict-free)
                *(unsigned long long*)&uw[1280 + l16*40 + h*16 + quad*4] = pk;
            }
            // A-frag chunk c: h0c[edge=l16][ch32 = quad*8 + j]
            // b128 read = 8 accesses/bank uniform (conflict-free)
            short8 afk = *(const short8*)&uw[1280 + l16*40 + quad*8];
            // l1: bw frags from L2 (wave-uniform base + lane*16, coalesced);
            // staged in 4-wide groups to bound VGPR (16 in flight).
            __builtin_amdgcn_s_setprio(1);   // MFMA-dominated run
            #pragma unroll
            for (int g = 0; g < 2; ++g){
                short8 bwv[4];
                #pragma unroll
                for (int u = 0; u < 4; ++u){
                    int tc2 = g*4 + u;
                    bwv[u] = *(const short8*)&w1p[tc2*2048 + c*512 + lane*8];
                }
                #pragma unroll
                for (int u = 0; u < 4; ++u){
                    int tc2 = g*4 + u;
                    acc1[tc2] = __builtin_amdgcn_mfma_f32_16x16x32_bf16(afk, bwv[u], acc1[tc2], 0, 0, 0);
                }
            }
            __builtin_amdgcn_s_setprio(0);
        }

        // bias + silu + ion-sum over rows, store one_el f32
        #pragma unroll
        for (int tc = 0; tc < 8; ++tc){
            float v = 0.f;
            #pragma unroll
            for (int rr = 0; rr < 4; ++rr) v += fast_silu(acc1[tc][rr] + bias1[tc]);
            v += __shfl_xor(v, 16, 64);   // quad0+1 -> unit 2w; quad2+3 -> unit 2w+1
            if ((quad & 1) == 0){
                size_t gu = (size_t)(ubase + 2*w + (quad >> 1));
                out[gu*ROWLEN + tc*16 + l16] = v;
            }
        }

        cur ^= 640;                    // swap feat buffers
        cx = nx; cy = ny; cz = nz;     // rotate r pipeline
    }
}

extern "C" void kernel_launch(void* const* d_in, const int* in_sizes, int n_in,
                              void* d_out, int out_size, void* d_ws, size_t ws_size,
                              hipStream_t stream)
{
    const float* r    = (const float*)d_in[0];
    const float* Rion = (const float*)d_in[1];
    const float* Z    = (const float*)d_in[2];
    const float* W0   = (const float*)d_in[3];
    const float* b0   = (const float*)d_in[4];
    const float* W1   = (const float*)d_in[5];
    const float* b1   = (const float*)d_in[6];
    const float* Wion = (const float*)d_in[7];
    const float* bion = (const float*)d_in[8];
    float* out = (float*)d_out;
    unsigned short* w1f = (unsigned short*)d_ws;   // 32768 B of workspace

    prep_w1<<<dim3(64), dim3(256), 0, stream>>>(W1, w1f);
    el_kernel<<<dim3(768), dim3(512), 0, stream>>>(r, Rion, W0, b0, b1, w1f,
                                                   Z, Wion, bion, out);
}

// Round 8
// 310.968 us; speedup vs baseline: 1.1514x; 1.1514x over previous
//
#include <hip/hip_runtime.h>

// InputPreprocessor — B=2048, N=32, M=8, D_PAIR=37, H=128.
// features_el_el in the reference is DEAD CODE. Live outputs (both f32):
//   out0 = features_el  [B,N,424]  (ion-summed 2-layer silu MLP || flat feats)
//   out1 = features_ion [B,8,32]
// R14: 20 waves/CU via SMALL blocks. R13's lesson: gfx950 unified VGPR+AGPR
// file — (512,6) caps TOTAL regs at 512/6~85 vs ~95-105 demand -> 25-reg
// spill catastrophe (rocprof VGPR_Count shows only the arch half: 40).
//  - block 256 (4 waves), __launch_bounds__(256,5): cap 512/5 ~= 100 total
//    regs >= ~92 demand. LDS = W0L 16384 + UNI 4x3840 = 31744 B ->
//    5 blocks/CU = 20 waves/CU (5/SIMD, +25% TLP over R12's 16).
//  - W1 B-frags from L2 (prep_w1 -> d_ws; wave-uniform dwordx4 loads, 2-wide
//    staging). W0 stays in LDS.
//  - register diet: muA/isA recomputed per use (rematerializable), bias1
//    loaded per iteration (opaque-ptr asm blocks LICM re-hoist), no r
//    prefetch registers (5 waves/SIMD hides the load latency).
//  - grid 1280 = exactly 5/CU; blocks 0..511 run 7 iters, 512..1279 run 6
//    (512*56 + 768*48 = 65536 units; 8 units per block-iter).
// Carried from R12: cross-iter feat pipeline (featA/featB disjoint double
// buffer, branchless body, idempotent wrap), rolling h0c l0->l1 handoff
// (stride-40, bank-uniform), v_cvt_pk_bf16_f32, bias0 via 1.0-feature,
// ion folded in, setprio around l1 MFMA runs.
// Spill tripwire: FETCH_SIZE must stay ~1 MB (else revert to R12).

typedef __attribute__((ext_vector_type(8))) short short8;
typedef __attribute__((ext_vector_type(4))) float f32x4;

#define ROWLEN    424
#define OUT_EL    27787264    // 65536*424

__device__ __forceinline__ unsigned short f2bf(float f){   // prologue staging only
    unsigned int u = __builtin_bit_cast(unsigned int, f);
    u += 0x7fffu + ((u >> 16) & 1u);     // RNE
    return (unsigned short)(u >> 16);
}
__device__ __forceinline__ unsigned int cvtpk_bf16(float lo, float hi){
    unsigned int r;
    asm("v_cvt_pk_bf16_f32 %0, %1, %2" : "=v"(r) : "v"(lo), "v"(hi));
    return r;   // [15:0]=bf16(lo), [31:16]=bf16(hi), RNE
}
__device__ __forceinline__ unsigned short bf16s(float x){
    return (unsigned short)cvtpk_bf16(x, x);
}
__device__ __forceinline__ float fast_silu(float x){
    return x * __builtin_amdgcn_rcpf(1.0f + __expf(-x));
}

// W1 bf16 B-frag layout into d_ws: short i = [tc][c][lane][j],
// k = c*32 + (lane>>4)*8 + j, n = tc*16 + (lane&15).
__global__ __launch_bounds__(256)
void prep_w1(const float* __restrict__ W1, unsigned short* __restrict__ w1f)
{
    int i = blockIdx.x*256 + threadIdx.x;        // 16384 shorts total
    int j = i & 7, ln = (i >> 3) & 63, c = (i >> 9) & 3, tc = i >> 11;
    int k = c*32 + (ln >> 4)*8 + j, n = tc*16 + (ln & 15);
    w1f[i] = f2bf(W1[k*128 + n]);
}

__global__ __launch_bounds__(256, 5)
void el_kernel(const float* __restrict__ r,
               const float* __restrict__ Rion,
               const float* __restrict__ W0,
               const float* __restrict__ b0,
               const float* __restrict__ b1,
               const unsigned short* __restrict__ w1f,
               const float* __restrict__ Z,
               const float* __restrict__ Wion,
               const float* __restrict__ bion,
               float* __restrict__ out)
{
    // MFMA-read layouts are [tile][chunk][lane64][8 shorts]: b128 = base+lane*16.
    __shared__ __align__(16) unsigned short W0L[8][2][64][8];   // 16384 B
    // Per-wave 3840B, three DISJOINT regions (no aliasing, no barriers):
    //   shorts [0,640)     : featA (k<32: [4][16][8]; tails+1.0+pad: [16][8])
    //   shorts [640,1280)  : featB (same layout; double buffer)
    //   shorts [1280,1920) : h0c rolling [16 edges][40] (l0->l1 chunk handoff)
    __shared__ __align__(16) unsigned short UNI[4][1920];       // 15360 B
    // total 31744 B -> 5 blocks (1280 thr) / CU = 20 waves/CU (5/SIMD)

    const int t    = threadIdx.x;
    const int lane = t & 63;
    const int w    = t >> 6;       // wave 0..3, owns units 2w,2w+1 (16 edges)
    const int quad = lane >> 4;
    const int l16  = lane & 15;

    // ---- stage W0L: A-frag for layer 0 (M=channel, K=feature) ----
    for (int i = t; i < 8*2*64*8; i += 256){
        int j = i & 7, ln = (i >> 3) & 63, ch = (i >> 9) & 1, tc = i >> 10;
        int q = ln >> 4, n = tc*16 + (ln & 15);
        float v = 0.f;
        if (ch == 0)            v = W0[(q*8 + j)*128 + n];
        else if (q == 0){
            if      (j < 5)     v = W0[(32 + j)*128 + n];
            else if (j == 5)    v = b0[n];                 // bias via 1.0-feature
        }
        ((unsigned short*)W0L)[i] = f2bf(v);
    }
    // ---- constant tail slots, BOTH feat buffers, once:
    // slot 5 = 1.0 (bias feature), slots 6,7 = 0.0 (k=38,39 pad).
    // Without init, it=0 reads raw LDS garbage; bf16 Inf/NaN x 0.0 weight
    // row = NaN inside the layer-0 MFMA (R8 lesson).
    if (t < 64){
        int ww = t >> 4, e = t & 15;
        #pragma unroll
        for (int b = 0; b < 2; ++b){
            UNI[ww][b*640 + 512 + e*8 + 5] = 0x3F80;
            UNI[ww][b*640 + 512 + e*8 + 6] = 0;
            UNI[ww][b*640 + 512 + e*8 + 7] = 0;
        }
    }

    // ---- ion output folded in: blocks 0..1023 write 2 elems/thread ----
    {
        int tid = blockIdx.x*256 + t;
        if (tid < 262144){
            int e0 = tid*2;                    // even -> j0 < 31, no wrap
            int j0 = e0 & 31, mm = (e0 >> 5) & 7;
            float z = Z[mm];
            float2 v;
            v.x = fast_silu(z * Wion[j0]     + bion[j0]);
            v.y = fast_silu(z * Wion[j0 + 1] + bion[j0 + 1]);
            *(float2*)&out[OUT_EL + e0] = v;
        }
    }

    // feature-phase mapping: 4 threads per edge; wave-local (frow>>4 == w)
    const int frow  = t >> 2;      // edge 0..63 = ul*8 + m
    const int phase = t & 3;
    const int ul    = frow >> 3;   // block-local unit 0..7
    const int m     = frow & 7;
    const int e16   = frow & 15;   // wave-local edge
    const float Rx = Rion[m*3+0];
    const float Ry = Rion[m*3+1];
    const float Rz = Rion[m*3+2];

    unsigned short* const uw = &UNI[w][0];

    const f32x4 zeroc = {0.f,0.f,0.f,0.f};

    // work split: blocks 0..511 -> 7 iters, 512..1279 -> 6 iters
    // (512*56 + 768*48 = 65536 units; 8 units per block-iter)
    const int bid    = blockIdx.x;
    const int niter  = (bid < 512) ? 7 : 6;
    const int ubase0 = (bid < 512) ? bid*56 : 28672 + (bid - 512)*48;

    // Branchless feature pass: computes edge (gu, m)'s 37 features, stores
    // exact f32 to out and bf16 to feat buffer at short-offset fb.
    // RBF constants recomputed per use (rematerializable — register diet).
    auto feat_pass = [&](int gu, int fb, float px, float py, float pz){
        float dx = px - Rx, dy = py - Ry, dz = pz - Rz;
        float d2 = dx*dx + dy*dy + dz*dz;
        float d  = __builtin_amdgcn_sqrtf(d2);
        float* orow = &out[(size_t)gu*ROWLEN + 128 + m*37];
        #pragma unroll
        for (int kk = 0; kk < 8; ++kk){
            float q   = (float)(phase + 4*kk) * (1.0f/31.0f);
            float mu  = q*q*5.0f;
            float is  = 7.0f * __builtin_amdgcn_rcpf(1.0f + 5.0f*q);
            float uu  = (d - mu) * is;
            float val = d2 * __expf(-d - uu*uu);
            orow[phase + 4*kk] = val;
            uw[fb + (kk >> 1)*128 + e16*8 + phase + ((kk & 1) << 2)] = bf16s(val);
        }
        // tails, branchless: this phase's slot + redundant dz (idempotent x4)
        float tv = (phase == 0) ? d :
                   (phase == 1) ? __builtin_amdgcn_rcpf(d + 0.01f) :
                   (phase == 2) ? dx : dy;
        orow[32 + phase] = tv;
        orow[36]         = dz;
        uw[fb + 512 + e16*8 + phase] = bf16s(tv);
        uw[fb + 512 + e16*8 + 4]     = bf16s(dz);
    };

    // ---- prologue: feat(0) into featA ----
    {
        int gu = ubase0 + ul;
        feat_pass(gu, 0, r[gu*3+0], r[gu*3+1], r[gu*3+2]);
    }

    __syncthreads();   // weights staged; loop body is wave-local, barrier-free

    int cur = 0;       // short-offset of current feat buffer (0 or 640)
    for (int it = 0; it < niter; ++it){
        const int ubase = ubase0 + it * 8;

        // opaque barriers: keep w1f/b1 loads inside the loop (block LICM from
        // hoisting 32 frags / 8 biases across iterations — R11/R13 spill trap)
        const unsigned short* w1p = w1f;
        const float*          b1p = b1;
        asm volatile("" : "+s"(w1p), "+s"(b1p));

        // current iteration's B-frags (featA/B[cur]; written a full iter ago)
        short8 bf0 = *(const short8*)&uw[cur + quad*128 + l16*8];   // k = quad*8+j
        short8 bf1 = *(const short8*)&uw[cur + 512 + l16*8];        // k = 32+j

        // feat for (it+1) mod niter into the OTHER buffer; last iter
        // recomputes feat(0) with identical values (idempotent stores).
        // r loaded directly (no prefetch regs; 5 waves/SIMD hide latency).
        {
            int i1 = it + 1; if (i1 >= niter) i1 = 0;
            int gu = ubase0 + i1*8 + ul;
            feat_pass(gu, cur ^ 640, r[gu*3+0], r[gu*3+1], r[gu*3+2]);
        }

        // ---------- fused layer0/layer1, rolling h0 chunk ----------
        f32x4 acc1[8];
        #pragma unroll
        for (int i = 0; i < 8; ++i) acc1[i] = zeroc;

        #pragma unroll
        for (int c = 0; c < 4; ++c){
            // l0 steps tc=2c, 2c+1 produce exactly k-chunk c = [32c, 32c+32)
            #pragma unroll
            for (int h = 0; h < 2; ++h){
                const int tc = 2*c + h;
                short8 a0 = *(const short8*)&W0L[tc][0][lane][0];
                short8 a1 = *(const short8*)&W0L[tc][1][lane][0];
                f32x4 acc = __builtin_amdgcn_mfma_f32_16x16x32_bf16(a0, bf0, zeroc, 0, 0, 0);
                acc       = __builtin_amdgcn_mfma_f32_16x16x32_bf16(a1, bf1, acc,   0, 0, 0);
                // C-layout: lane holds ch n = tc*16 + quad*4 + rr, edge = l16.
                unsigned int p01 = cvtpk_bf16(fast_silu(acc[0]), fast_silu(acc[1]));
                unsigned int p23 = cvtpk_bf16(fast_silu(acc[2]), fast_silu(acc[3]));
                unsigned long long pk = (unsigned long long)p01 |
                                        ((unsigned long long)p23 << 32);
                // h0c[edge=l16][ch32 = h*16+quad*4 ..+3]; stride-40 rows:
                // b64 write = 4 accesses/bank uniform (conflict-free)
                *(unsigned long long*)&uw[1280 + l16*40 + h*16 + quad*4] = pk;
            }
            // A-frag chunk c: h0c[edge=l16][ch32 = quad*8 + j]
            // b128 read = 8 accesses/bank uniform (conflict-free)
            short8 afk = *(const short8*)&uw[1280 + l16*40 + quad*8];
            // l1: bw frags from L2 (wave-uniform base + lane*16, coalesced);
            // staged in 2-wide groups to bound transient VGPR (8 in flight).
            __builtin_amdgcn_s_setprio(1);   // MFMA-dominated run
            #pragma unroll
            for (int g = 0; g < 4; ++g){
                short8 bwv[2];
                #pragma unroll
                for (int u = 0; u < 2; ++u){
                    int tc2 = g*2 + u;
                    bwv[u] = *(const short8*)&w1p[tc2*2048 + c*512 + lane*8];
                }
                #pragma unroll
                for (int u = 0; u < 2; ++u){
                    int tc2 = g*2 + u;
                    acc1[tc2] = __builtin_amdgcn_mfma_f32_16x16x32_bf16(afk, bwv[u], acc1[tc2], 0, 0, 0);
                }
            }
            __builtin_amdgcn_s_setprio(0);
        }

        // bias + silu + ion-sum over rows, store one_el f32
        #pragma unroll
        for (int tc = 0; tc < 8; ++tc){
            float bias = b1p[tc*16 + l16];
            float v = 0.f;
            #pragma unroll
            for (int rr = 0; rr < 4; ++rr) v += fast_silu(acc1[tc][rr] + bias);
            v += __shfl_xor(v, 16, 64);   // quad0+1 -> unit 2w; quad2+3 -> unit 2w+1
            if ((quad & 1) == 0){
                size_t gu = (size_t)(ubase + 2*w + (quad >> 1));
                out[gu*ROWLEN + tc*16 + l16] = v;
            }
        }

        cur ^= 640;                    // swap feat buffers
    }
}

extern "C" void kernel_launch(void* const* d_in, const int* in_sizes, int n_in,
                              void* d_out, int out_size, void* d_ws, size_t ws_size,
                              hipStream_t stream)
{
    const float* r    = (const float*)d_in[0];
    const float* Rion = (const float*)d_in[1];
    const float* Z    = (const float*)d_in[2];
    const float* W0   = (const float*)d_in[3];
    const float* b0   = (const float*)d_in[4];
    const float* W1   = (const float*)d_in[5];
    const float* b1   = (const float*)d_in[6];
    const float* Wion = (const float*)d_in[7];
    const float* bion = (const float*)d_in[8];
    float* out = (float*)d_out;
    unsigned short* w1f = (unsigned short*)d_ws;   // 32768 B of workspace

    prep_w1<<<dim3(64), dim3(256), 0, stream>>>(W1, w1f);
    el_kernel<<<dim3(1280), dim3(256), 0, stream>>>(r, Rion, W0, b0, b1, w1f,
                                                    Z, Wion, bion, out);
}

// Round 9
// 173.972 us; speedup vs baseline: 2.0581x; 1.7875x over previous
//
#include <hip/hip_runtime.h>

// InputPreprocessor — B=2048, N=32, M=8, D_PAIR=37, H=128.
// features_el_el in the reference is DEAD CODE. Live outputs (both f32):
//   out0 = features_el  [B,N,424]  (ion-summed 2-layer silu MLP || flat feats)
//   out1 = features_ion [B,8,32]
// R15 = R12 (proven 76.8 µs el) + issue-count shaves. Occupancy is CLOSED:
// R11/(1024,8), R13/(512,6), R14/(256,5) all spilled (unified VGPR+AGPR
// demand ~100-110 vs caps 64/85/96) -> only (512,4)'s 128-reg cap fits ->
// 16 waves/CU is structural. Remaining levers are instruction counts:
//  - contiguous RBF ownership: phase p owns k=8p..8p+7 (was p+4j). The 8
//    bf16 RBF values = exactly one featL chunk -> ONE ds_write_b128 replaces
//    8 ds_write_b16; 8 cvt_pk -> 4. f32 stores stay dword (orow not 16B-
//    aligned for odd m) off one base reg.
//  - pair-rcp silu: silu(a),silu(b) share one denominator rcp:
//    pA=1+e^-a, pB=1+e^-b, rp=rcp(pA*pB); silu(a)=a*pB*rp, silu(b)=b*pA*rp.
//    2 exp + 1 rcp (+3 mul) per pair vs 2+2: -32 rcp/wave-iter on the
//    quarter-rate trans pipe (trans was ~36% of issue).
// Carried from R12: cross-iter feat pipeline (featA/featB disjoint double
// buffer, branchless body, idempotent wrap), rolling h0c l0->l1 handoff
// (stride-40, bank-uniform), W0L/W1L in LDS, v_cvt_pk_bf16_f32, bias0 via
// 1.0-feature, b1/mu/sigma hoisted, 2-deep r prefetch, ion folded in,
// setprio around l1, LDS 79872 B = 2 blocks/CU, __launch_bounds__(512,4).

typedef __attribute__((ext_vector_type(8))) short short8;
typedef __attribute__((ext_vector_type(4))) float f32x4;
typedef __attribute__((ext_vector_type(4))) int   int4v;

#define ITERS     8
#define UNITS_IT  16          // units per block-iteration (128 edges)
#define ROWLEN    424
#define OUT_EL    27787264    // 65536*424

__device__ __forceinline__ unsigned short f2bf(float f){   // prologue staging only
    unsigned int u = __builtin_bit_cast(unsigned int, f);
    u += 0x7fffu + ((u >> 16) & 1u);     // RNE
    return (unsigned short)(u >> 16);
}
__device__ __forceinline__ unsigned int cvtpk_bf16(float lo, float hi){
    unsigned int r;
    asm("v_cvt_pk_bf16_f32 %0, %1, %2" : "=v"(r) : "v"(lo), "v"(hi));
    return r;   // [15:0]=bf16(lo), [31:16]=bf16(hi), RNE
}
__device__ __forceinline__ unsigned short bf16s(float x){
    return (unsigned short)cvtpk_bf16(x, x);
}
__device__ __forceinline__ float fast_silu(float x){
    return x * __builtin_amdgcn_rcpf(1.0f + __expf(-x));
}
// two silus, one rcp (shared denominator). Overflow needs x0+x1 < -177
// with each > -88.7 — unreachable for these activations (|acc| <~ 30).
__device__ __forceinline__ void silu2(float x0, float x1, float& s0, float& s1){
    float pA = 1.0f + __expf(-x0);
    float pB = 1.0f + __expf(-x1);
    float rp = __builtin_amdgcn_rcpf(pA * pB);
    s0 = x0 * pB * rp;
    s1 = x1 * pA * rp;
}

__global__ __launch_bounds__(512, 4)
void el_kernel(const float* __restrict__ r,
               const float* __restrict__ Rion,
               const float* __restrict__ W0,
               const float* __restrict__ b0,
               const float* __restrict__ W1,
               const float* __restrict__ b1,
               const float* __restrict__ Z,
               const float* __restrict__ Wion,
               const float* __restrict__ bion,
               float* __restrict__ out)
{
    // MFMA-read layouts are [tile][chunk][lane64][8 shorts]: b128 = base+lane*16.
    __shared__ __align__(16) unsigned short W0L[8][2][64][8];   // 16384 B
    __shared__ __align__(16) unsigned short W1L[8][4][64][8];   // 32768 B
    // Per-wave 3840B, three DISJOINT regions (no aliasing, no barriers):
    //   shorts [0,640)     : featA (k<32: [4][16][8]; tails+1.0+pad: [16][8])
    //   shorts [640,1280)  : featB (same layout; double buffer)
    //   shorts [1280,1920) : h0c rolling [16 edges][40] (l0->l1 chunk handoff)
    __shared__ __align__(16) unsigned short UNI[8][1920];       // 30720 B
    // total 79872 B -> 2 blocks (1024 thr) / CU = 16 waves/CU

    const int t    = threadIdx.x;
    const int lane = t & 63;
    const int w    = t >> 6;       // wave 0..7, owns units 2w,2w+1 (16 edges)
    const int quad = lane >> 4;
    const int l16  = lane & 15;

    // ---- stage W0L: A-frag for layer 0 (M=channel, K=feature) ----
    for (int i = t; i < 8*2*64*8; i += 512){
        int j = i & 7, ln = (i >> 3) & 63, ch = (i >> 9) & 1, tc = i >> 10;
        int q = ln >> 4, n = tc*16 + (ln & 15);
        float v = 0.f;
        if (ch == 0)            v = W0[(q*8 + j)*128 + n];
        else if (q == 0){
            if      (j < 5)     v = W0[(32 + j)*128 + n];
            else if (j == 5)    v = b0[n];                 // bias via 1.0-feature
        }
        ((unsigned short*)W0L)[i] = f2bf(v);
    }
    // ---- stage W1L: B-frag for layer 1 (K=channel, N=out-channel) ----
    for (int i = t; i < 8*4*64*8; i += 512){
        int j = i & 7, ln = (i >> 3) & 63, c = (i >> 9) & 3, tc = i >> 11;
        int k = c*32 + (ln >> 4)*8 + j, n = tc*16 + (ln & 15);
        ((unsigned short*)W1L)[i] = f2bf(W1[k*128 + n]);
    }
    // ---- constant tail slots, BOTH feat buffers, once:
    // slot 5 = 1.0 (bias feature), slots 6,7 = 0.0 (k=38,39 pad).
    // Without init, it=0 reads raw LDS garbage; bf16 Inf/NaN x 0.0 weight
    // row = NaN inside the layer-0 MFMA (R8 lesson).
    if (t < 128){
        int ww = t >> 4, e = t & 15;
        #pragma unroll
        for (int b = 0; b < 2; ++b){
            UNI[ww][b*640 + 512 + e*8 + 5] = 0x3F80;
            UNI[ww][b*640 + 512 + e*8 + 6] = 0;
            UNI[ww][b*640 + 512 + e*8 + 7] = 0;
        }
    }

    // ---- ion output folded in: 2 elements per thread (524288 total) ----
    {
        int e0 = (blockIdx.x*512 + t)*2;           // even -> j0 < 31, no wrap
        int j0 = e0 & 31, mm = (e0 >> 5) & 7;
        float z = Z[mm];
        float2 v;
        v.x = fast_silu(z * Wion[j0]     + bion[j0]);
        v.y = fast_silu(z * Wion[j0 + 1] + bion[j0 + 1]);
        *(float2*)&out[OUT_EL + e0] = v;
    }

    // feature-phase mapping: 4 threads per edge; wave-local (frow>>4 == w)
    const int frow  = t >> 2;      // edge 0..127 = ul*8 + m
    const int phase = t & 3;
    const int ul    = frow >> 3;   // block-local unit 0..15
    const int m     = frow & 7;
    const int e16   = frow & 15;   // wave-local edge
    const float Rx = Rion[m*3+0];
    const float Ry = Rion[m*3+1];
    const float Rz = Rion[m*3+2];

    unsigned short* const uw = &UNI[w][0];

    const f32x4 zeroc = {0.f,0.f,0.f,0.f};

    // hoist layer-1 bias (8 VGPRs)
    float bias1[8];
    #pragma unroll
    for (int tc = 0; tc < 8; ++tc) bias1[tc] = b1[tc*16 + l16];

    // hoist per-thread RBF constants: k = 8*phase + kk, kk = 0..7 (contiguous)
    float muA[8], isA[8];
    #pragma unroll
    for (int kk = 0; kk < 8; ++kk){
        float q = (float)(phase*8 + kk) * (1.0f/31.0f);
        muA[kk] = q*q*5.0f;
        isA[kk] = 7.0f * __builtin_amdgcn_rcpf(1.0f + 5.0f*q);
    }

    const int ubase0 = blockIdx.x * (UNITS_IT * ITERS);

    // Branchless feature pass: computes edge (gu, m)'s 37 features, stores
    // exact f32 to out and bf16 to feat buffer at short-offset fb.
    // This lane owns RBF k = 8*phase..8*phase+7 -> its 8 bf16 values are
    // exactly featL chunk[phase], written as ONE ds_write_b128.
    auto feat_pass = [&](int gu, int fb, float px, float py, float pz){
        float dx = px - Rx, dy = py - Ry, dz = pz - Rz;
        float d2 = dx*dx + dy*dy + dz*dz;
        float d  = __builtin_amdgcn_sqrtf(d2);
        float* orow = &out[(size_t)gu*ROWLEN + 128 + m*37];
        int4v pkv;
        #pragma unroll
        for (int jp = 0; jp < 4; ++jp){
            float uu0 = (d - muA[2*jp])   * isA[2*jp];
            float v0  = d2 * __expf(-d - uu0*uu0);
            float uu1 = (d - muA[2*jp+1]) * isA[2*jp+1];
            float v1  = d2 * __expf(-d - uu1*uu1);
            orow[phase*8 + 2*jp]     = v0;
            orow[phase*8 + 2*jp + 1] = v1;
            pkv[jp] = (int)cvtpk_bf16(v0, v1);
        }
        *(int4v*)&uw[fb + phase*128 + e16*8] = pkv;   // chunk[phase], 16B aligned
        // tails, branchless: this phase's slot + redundant dz (idempotent x4)
        float tv = (phase == 0) ? d :
                   (phase == 1) ? __builtin_amdgcn_rcpf(d + 0.01f) :
                   (phase == 2) ? dx : dy;
        orow[32 + phase] = tv;
        orow[36]         = dz;
        uw[fb + 512 + e16*8 + phase] = bf16s(tv);
        uw[fb + 512 + e16*8 + 4]     = bf16s(dz);
    };

    // ---- prologue: feat(0) into featA; prefetch r(1) ----
    {
        int gu = ubase0 + ul;
        feat_pass(gu, 0, r[gu*3+0], r[gu*3+1], r[gu*3+2]);
    }
    float cx, cy, cz;
    {
        int gu = ubase0 + UNITS_IT + ul;     // r(1) (ITERS>=2)
        cx = r[gu*3+0]; cy = r[gu*3+1]; cz = r[gu*3+2];
    }

    __syncthreads();   // weights staged; loop body is wave-local, barrier-free

    int cur = 0;       // short-offset of current feat buffer (0 or 640)
    for (int it = 0; it < ITERS; ++it){
        const int ubase = ubase0 + it * UNITS_IT;

        // prefetch r((it+2) & 7) — wrapped, branchless (last iters re-load r(0/1))
        int gun = ubase0 + (((it + 2) & (ITERS-1)) * UNITS_IT) + ul;
        float nx = r[gun*3+0], ny = r[gun*3+1], nz = r[gun*3+2];

        // current iteration's B-frags (featA/B[cur]; written a full iter ago)
        short8 bf0 = *(const short8*)&uw[cur + quad*128 + l16*8];   // k = quad*8+j
        short8 bf1 = *(const short8*)&uw[cur + 512 + l16*8];        // k = 32+j

        // feat for (it+1)&7 into the OTHER buffer. it=ITERS-1 recomputes
        // feat(0) with identical values (idempotent stores) — keeps the body
        // branchless so the scheduler can interleave it with l0/l1 below.
        {
            int gu = ubase0 + (((it + 1) & (ITERS-1)) * UNITS_IT) + ul;
            feat_pass(gu, cur ^ 640, cx, cy, cz);
        }

        // ---------- fused layer0/layer1, rolling h0 chunk ----------
        f32x4 acc1[8];
        #pragma unroll
        for (int i = 0; i < 8; ++i) acc1[i] = zeroc;

        #pragma unroll
        for (int c = 0; c < 4; ++c){
            // l0 steps tc=2c, 2c+1 produce exactly k-chunk c = [32c, 32c+32)
            #pragma unroll
            for (int h = 0; h < 2; ++h){
                const int tc = 2*c + h;
                short8 a0 = *(const short8*)&W0L[tc][0][lane][0];
                short8 a1 = *(const short8*)&W0L[tc][1][lane][0];
                f32x4 acc = __builtin_amdgcn_mfma_f32_16x16x32_bf16(a0, bf0, zeroc, 0, 0, 0);
                acc       = __builtin_amdgcn_mfma_f32_16x16x32_bf16(a1, bf1, acc,   0, 0, 0);
                // C-layout: lane holds ch n = tc*16 + quad*4 + rr, edge = l16.
                float s0, s1, s2, s3;
                silu2(acc[0], acc[1], s0, s1);
                silu2(acc[2], acc[3], s2, s3);
                unsigned int p01 = cvtpk_bf16(s0, s1);
                unsigned int p23 = cvtpk_bf16(s2, s3);
                unsigned long long pk = (unsigned long long)p01 |
                                        ((unsigned long long)p23 << 32);
                // h0c[edge=l16][ch32 = h*16+quad*4 ..+3]; stride-40 rows:
                // b64 write = 4 accesses/bank uniform (conflict-free)
                *(unsigned long long*)&uw[1280 + l16*40 + h*16 + quad*4] = pk;
            }
            // A-frag chunk c: h0c[edge=l16][ch32 = quad*8 + j]
            // b128 read = 8 accesses/bank uniform (conflict-free)
            short8 afk = *(const short8*)&uw[1280 + l16*40 + quad*8];
            __builtin_amdgcn_s_setprio(1);   // pure-MFMA run; waves phase-diverse
            #pragma unroll
            for (int tc2 = 0; tc2 < 8; ++tc2){
                short8 bw = *(const short8*)&W1L[tc2][c][lane][0];
                acc1[tc2] = __builtin_amdgcn_mfma_f32_16x16x32_bf16(afk, bw, acc1[tc2], 0, 0, 0);
            }
            __builtin_amdgcn_s_setprio(0);
        }

        // bias + silu + ion-sum over rows (rr spans edges), store one_el f32
        #pragma unroll
        for (int tc = 0; tc < 8; ++tc){
            float s0, s1, s2, s3;
            silu2(acc1[tc][0] + bias1[tc], acc1[tc][1] + bias1[tc], s0, s1);
            silu2(acc1[tc][2] + bias1[tc], acc1[tc][3] + bias1[tc], s2, s3);
            float v = (s0 + s1) + (s2 + s3);
            v += __shfl_xor(v, 16, 64);   // quad0+1 -> unit 2w; quad2+3 -> unit 2w+1
            if ((quad & 1) == 0){
                size_t gu = (size_t)(ubase + 2*w + (quad >> 1));
                out[gu*ROWLEN + tc*16 + l16] = v;
            }
        }

        cur ^= 640;                    // swap feat buffers
        cx = nx; cy = ny; cz = nz;     // rotate r pipeline
    }
}

extern "C" void kernel_launch(void* const* d_in, const int* in_sizes, int n_in,
                              void* d_out, int out_size, void* d_ws, size_t ws_size,
                              hipStream_t stream)
{
    const float* r    = (const float*)d_in[0];
    const float* Rion = (const float*)d_in[1];
    const float* Z    = (const float*)d_in[2];
    const float* W0   = (const float*)d_in[3];
    const float* b0   = (const float*)d_in[4];
    const float* W1   = (const float*)d_in[5];
    const float* b1   = (const float*)d_in[6];
    const float* Wion = (const float*)d_in[7];
    const float* bion = (const float*)d_in[8];
    float* out = (float*)d_out;

    el_kernel<<<dim3(512), dim3(512), 0, stream>>>(r, Rion, W0, b0, W1, b1,
                                                   Z, Wion, bion, out);
}